// Round 7
// baseline (147.535 us; speedup 1.0000x reference)
//
#include <hip/hip_runtime.h>
#include <math.h>

#define NROWS 8192
#define FIN   512
#define FOUT  256
#define NCHUNK 256
#define CHROWS 32   // NROWS / NCHUNK

typedef _Float16 f16;
typedef _Float16 f16x8 __attribute__((ext_vector_type(8)));
typedef float    f32x4 __attribute__((ext_vector_type(4)));

// ---- prep: x -> f16, W -> Wt f16 transposed [N][K]; blocks 256-319 zero fg ----
__global__ __launch_bounds__(256) void prep(const float* __restrict__ x,
                                            const float* __restrict__ W,
                                            f16* __restrict__ xh,
                                            f16* __restrict__ Wt,
                                            float* __restrict__ fg) {
    const int b = blockIdx.x, t = threadIdx.x;
    if (b < 256) {
        const size_t base = (size_t)b * 16384;
#pragma unroll 4
        for (int i = 0; i < 16; ++i) {
            const size_t idx = base + (size_t)i * 1024 + t * 4;
            float4 v = *(const float4*)&x[idx];
            union { f16 h[4]; ushort4 u; } cv;
            cv.h[0] = (f16)v.x; cv.h[1] = (f16)v.y;
            cv.h[2] = (f16)v.z; cv.h[3] = (f16)v.w;
            *(ushort4*)&xh[idx] = cv.u;
        }
    } else {
        const int n = b - 256;   // 0..255
        Wt[(size_t)n * FIN + t]       = (f16)W[(size_t)t * FOUT + n];
        Wt[(size_t)n * FIN + t + 256] = (f16)W[(size_t)(t + 256) * FOUT + n];
        if (n < 64) fg[n * 256 + t] = 0.f;   // zero f and g (2*NROWS floats)
    }
}

// ---- GEMM h = x@W via f16 MFMA, BK=128; h stored f16; XCD-swizzled grid ----
__global__ __launch_bounds__(256) void gemm_fg(const f16* __restrict__ xh,
                                               const f16* __restrict__ Wt,
                                               const float* __restrict__ a,
                                               f16* __restrict__ h,
                                               float* __restrict__ f,
                                               float* __restrict__ g) {
    __shared__ __align__(16) f16 As[64][136];
    __shared__ __align__(16) f16 Bs[64][136];
    __shared__ float sf[2][64], sg[2][64];
    const int tid = threadIdx.x;
    // XCD swizzle: blocks i with i%8==x go to XCD x (round-robin heuristic).
    // Give each XCD 16 m-rows x all 4 n-blocks so A re-reads stay in its L2.
    const int bid = blockIdx.x;
    const int xcd = bid & 7;
    const int local = bid >> 3;          // 0..63
    const int m0 = (xcd * 16 + (local & 15)) * 64;
    const int n0 = (local >> 4) * 64;
    const int srow = tid >> 2, sseg = (tid & 3) * 8;
    const int w = tid >> 6, lane = tid & 63;
    const int wm = (w & 1) * 32, wn = (w >> 1) * 32;
    const int l15 = lane & 15, quad = lane >> 4;

    f16x8 pa[4], pb[4];
#pragma unroll
    for (int j = 0; j < 4; ++j) {
        pa[j] = *(const f16x8*)&xh[(size_t)(m0 + srow) * FIN + j * 32 + sseg];
        pb[j] = *(const f16x8*)&Wt[(size_t)(n0 + srow) * FIN + j * 32 + sseg];
    }

    f32x4 acc[2][2] = {};
    for (int k0 = 0; k0 < FIN; k0 += 128) {
        __syncthreads();
#pragma unroll
        for (int j = 0; j < 4; ++j) {
            *(f16x8*)&As[srow][j * 32 + sseg] = pa[j];
            *(f16x8*)&Bs[srow][j * 32 + sseg] = pb[j];
        }
        __syncthreads();
        if (k0 + 128 < FIN) {
#pragma unroll
            for (int j = 0; j < 4; ++j) {
                pa[j] = *(const f16x8*)&xh[(size_t)(m0 + srow) * FIN + k0 + 128 + j * 32 + sseg];
                pb[j] = *(const f16x8*)&Wt[(size_t)(n0 + srow) * FIN + k0 + 128 + j * 32 + sseg];
            }
        }
#pragma unroll
        for (int kk = 0; kk < 4; ++kk) {
            f16x8 af[2], bf[2];
#pragma unroll
            for (int ti = 0; ti < 2; ++ti)
                af[ti] = *(const f16x8*)&As[wm + ti * 16 + l15][kk * 32 + quad * 8];
#pragma unroll
            for (int tj = 0; tj < 2; ++tj)
                bf[tj] = *(const f16x8*)&Bs[wn + tj * 16 + l15][kk * 32 + quad * 8];
#pragma unroll
            for (int ti = 0; ti < 2; ++ti)
#pragma unroll
                for (int tj = 0; tj < 2; ++tj)
                    acc[ti][tj] = __builtin_amdgcn_mfma_f32_16x16x32_f16(af[ti], bf[tj], acc[ti][tj], 0, 0, 0);
        }
    }
    // write h as f16: D layout col=lane&15, row=quad*4+r
#pragma unroll
    for (int ti = 0; ti < 2; ++ti)
#pragma unroll
        for (int tj = 0; tj < 2; ++tj) {
            const int col = n0 + wn + tj * 16 + l15;
#pragma unroll
            for (int r = 0; r < 4; ++r) {
                const int row = m0 + wm + ti * 16 + quad * 4 + r;
                h[(size_t)row * FOUT + col] = (f16)acc[ti][tj][r];
            }
        }
    // fused f/g partials -> atomicAdd per row (fp32 accumulators, exact path)
    const float a1c0 = a[n0 + wn + l15];
    const float a1c1 = a[n0 + wn + 16 + l15];
    const float a2c0 = a[FOUT + n0 + wn + l15];
    const float a2c1 = a[FOUT + n0 + wn + 16 + l15];
    const int wnIdx = w >> 1;
#pragma unroll
    for (int ti = 0; ti < 2; ++ti) {
        float pf[4], pg[4];
#pragma unroll
        for (int r = 0; r < 4; ++r) {
            pf[r] = acc[ti][0][r] * a1c0 + acc[ti][1][r] * a1c1;
            pg[r] = acc[ti][0][r] * a2c0 + acc[ti][1][r] * a2c1;
        }
#pragma unroll
        for (int off = 8; off >= 1; off >>= 1)
#pragma unroll
            for (int r = 0; r < 4; ++r) {
                pf[r] += __shfl_xor(pf[r], off, 16);
                pg[r] += __shfl_xor(pg[r], off, 16);
            }
        if (l15 == 0)
#pragma unroll
            for (int r = 0; r < 4; ++r) {
                sf[wnIdx][wm + ti * 16 + quad * 4 + r] = pf[r];
                sg[wnIdx][wm + ti * 16 + quad * 4 + r] = pg[r];
            }
    }
    __syncthreads();
    if (tid < 64) {
        atomicAdd(&f[m0 + tid], sf[0][tid] + sf[1][tid]);
        atomicAdd(&g[m0 + tid], sg[0][tid] + sg[1][tid]);
    }
}

// ---- rank + scatter: rank_j = #{i: g_i<g_j || (==, i<j)} ----
__global__ __launch_bounds__(256) void rank_scatter(const float* __restrict__ g,
                                                    float* __restrict__ gs,
                                                    int* __restrict__ perm) {
    const int t = threadIdx.x;
    const int jl = t & 31;
    const int seg = t >> 5;
    const int j = blockIdx.x * 32 + jl;
    const float gj = g[j];
    const int base = seg * (NROWS / 8);
    int cnt = 0;
    for (int r = 0; r < NROWS / 8; r += 4) {
        const float4 v = *(const float4*)&g[base + r];
        const int i0 = base + r;
        cnt += (v.x < gj) || (v.x == gj && (i0 + 0) < j);
        cnt += (v.y < gj) || (v.y == gj && (i0 + 1) < j);
        cnt += (v.z < gj) || (v.z == gj && (i0 + 2) < j);
        cnt += (v.w < gj) || (v.w == gj && (i0 + 3) < j);
    }
    __shared__ int part[8][32];
    part[seg][jl] = cnt;
    __syncthreads();
    if (seg == 0) {
        int rank = 0;
#pragma unroll
        for (int s = 0; s < 8; ++s) rank += part[s][jl];
        gs[rank] = gj;
        perm[rank] = j;
    }
}

// ---- scan pass 1 (blocks 0-255): per-chunk sums; blocks 256-287: n0 searches ----
__global__ __launch_bounds__(256) void scan_pass1(const f16* __restrict__ h,
                                                  const int* __restrict__ perm,
                                                  const float* __restrict__ gs,
                                                  const float* __restrict__ f,
                                                  float* __restrict__ c0,
                                                  float* __restrict__ c1,
                                                  float* __restrict__ c1s,
                                                  int* __restrict__ n0arr) {
    const int b = blockIdx.x, c = threadIdx.x;
    if (b < 256) {
        const int base = b * CHROWS;
        __shared__ int p[CHROWS];
        __shared__ float wl[CHROWS];
        if (c < CHROWS) {
            p[c] = perm[base + c];
            wl[c] = expf(gs[base + c] - gs[NROWS - 1]);
        }
        __syncthreads();
        float s0 = 0.f, s1 = 0.f;
        for (int r = 0; r < CHROWS; ++r) {
            float v = (float)h[(size_t)p[r] * FOUT + c];
            s0 += v;
            s1 += wl[r] * v;
        }
        c0[b * FOUT + c] = s0;
        c1[b * FOUT + c] = s1;
        if (c == 0) {
            float t = 0.f;
            for (int r = 0; r < CHROWS; ++r) t += wl[r];
            c1s[b] = t;
        }
    } else {
        const int i = (b - 256) * 256 + c;   // 0..8191
        const float tt = -f[i];
        int lo = 0, hi = NROWS;
        while (lo < hi) {
            int mid = (lo + hi) >> 1;
            if (gs[mid] <= tt) lo = mid + 1; else hi = mid;
        }
        n0arr[i] = lo;
    }
}

// ---- scan pass 3: self-computes chunk offsets from c0/c1/c1s (L2-hot), then
//      element-granular P0 (exclusive prefix) / S1 (inclusive suffix) / S1s ----
__global__ __launch_bounds__(256) void scan_pass3(const f16* __restrict__ h,
                                                  const int* __restrict__ perm,
                                                  const float* __restrict__ gs,
                                                  const float* __restrict__ c0,
                                                  const float* __restrict__ c1,
                                                  const float* __restrict__ c1s,
                                                  float* __restrict__ P0,
                                                  float* __restrict__ S1,
                                                  float* __restrict__ S1s) {
    const int k = blockIdx.x, c = threadIdx.x;
    const int base = k * CHROWS;
    __shared__ int p[CHROWS];
    __shared__ float wl[CHROWS];
    __shared__ float red[256];
    if (c < CHROWS) {
        p[c] = perm[base + c];
        wl[c] = expf(gs[base + c] - gs[NROWS - 1]);
    }
    // chunk-level offsets (was scan_pass2): coalesced row reads, L2-resident
    float off0 = 0.f, off1 = 0.f;
#pragma unroll 4
    for (int j = 0; j < k; ++j) off0 += c0[j * FOUT + c];
#pragma unroll 4
    for (int j = k + 1; j < NCHUNK; ++j) off1 += c1[j * FOUT + c];
    // scalar S1s offset: sum of c1s over chunks > k (block reduce)
    red[c] = (c > k) ? c1s[c] : 0.f;
    __syncthreads();
#pragma unroll
    for (int s = 128; s > 0; s >>= 1) {
        if (c < s) red[c] += red[c + s];
        __syncthreads();
    }
    const float s1s_off = red[0];

    float run0 = off0;
    for (int r = 0; r < CHROWS; ++r) {
        P0[(size_t)(base + r) * FOUT + c] = run0;
        run0 += (float)h[(size_t)p[r] * FOUT + c];
    }
    float run1 = off1;
    for (int r = CHROWS - 1; r >= 0; --r) {
        run1 += wl[r] * (float)h[(size_t)p[r] * FOUT + c];
        S1[(size_t)(base + r) * FOUT + c] = run1;
    }
    if (c == 0) {
        float rs = s1s_off;
        for (int r = CHROWS - 1; r >= 0; --r) { rs += wl[r]; S1s[base + r] = rs; }
    }
    if (k == NCHUNK - 1) {
        P0[(size_t)NROWS * FOUT + c] = run0;   // total column sum
        S1[(size_t)NROWS * FOUT + c] = 0.f;
        if (c == 0) S1s[NROWS] = 0.f;
    }
}

// ---- final: streaming combine + ELU, 4 rows/block ----
__global__ __launch_bounds__(256) void final_kernel(const float* __restrict__ f,
                                                    const float* __restrict__ gs,
                                                    const int* __restrict__ n0arr,
                                                    const float* __restrict__ P0,
                                                    const float* __restrict__ S1,
                                                    const float* __restrict__ S1s,
                                                    float* __restrict__ out) {
    const int b = blockIdx.x, c = threadIdx.x;
    const float gm = gs[NROWS - 1];
#pragma unroll
    for (int rr = 0; rr < 4; ++rr) {
        const int i = b * 4 + rr;
        const float fi = f[i];
        const int n0 = n0arr[i];
        const float m = fmaxf(0.f, fi + gm);
        const float A = expf(-m);
        const float B = expf(fi + gm - m);
        const float denom = A * (float)n0 + B * S1s[n0];
        const float numer = A * P0[(size_t)n0 * FOUT + c] + B * S1[(size_t)n0 * FOUT + c];
        const float v = numer / denom;
        out[(size_t)i * FOUT + c] = v > 0.f ? v : expm1f(v);
    }
}

extern "C" void kernel_launch(void* const* d_in, const int* in_sizes, int n_in,
                              void* d_out, int out_size, void* d_ws, size_t ws_size,
                              hipStream_t stream) {
    (void)in_sizes; (void)n_in; (void)out_size; (void)ws_size;
    const float* x = (const float*)d_in[0];
    const float* W = (const float*)d_in[1];
    const float* a = (const float*)d_in[2];
    float* out = (float*)d_out;

    char* ws = (char*)d_ws;
    size_t off = 0;
    auto alloc = [&](size_t bytes) -> void* {
        void* p = ws + off;
        off += (bytes + 255) & ~(size_t)255;
        return p;
    };
    f16*   xh   = (f16*)alloc((size_t)NROWS * FIN * 2);
    f16*   Wt   = (f16*)alloc((size_t)FOUT * FIN * 2);
    f16*   h    = (f16*)alloc((size_t)NROWS * FOUT * 2);
    float* P0   = (float*)alloc((size_t)(NROWS + 1) * FOUT * 4);
    float* S1   = (float*)alloc((size_t)(NROWS + 1) * FOUT * 4);
    float* fg   = (float*)alloc(2 * NROWS * 4);
    float* f    = fg;
    float* g    = fg + NROWS;
    float* gs   = (float*)alloc(NROWS * 4);
    int*   perm = (int*)alloc(NROWS * 4);
    int*   n0arr= (int*)alloc(NROWS * 4);
    float* c0   = (float*)alloc(NCHUNK * FOUT * 4);
    float* c1   = (float*)alloc(NCHUNK * FOUT * 4);
    float* c1s  = (float*)alloc(NCHUNK * 4);
    float* S1s  = (float*)alloc((NROWS + 1) * 4);

    prep<<<512, 256, 0, stream>>>(x, W, xh, Wt, fg);
    gemm_fg<<<512, 256, 0, stream>>>(xh, Wt, a, h, f, g);
    rank_scatter<<<NROWS / 32, 256, 0, stream>>>(g, gs, perm);
    scan_pass1<<<288, 256, 0, stream>>>(h, perm, gs, f, c0, c1, c1s, n0arr);
    scan_pass3<<<NCHUNK, 256, 0, stream>>>(h, perm, gs, c0, c1, c1s, P0, S1, S1s);
    final_kernel<<<NROWS / 4, 256, 0, stream>>>(f, gs, n0arr, P0, S1, S1s, out);
}